// Round 3
// baseline (25367.032 us; speedup 1.0000x reference)
//
#include <hip/hip_runtime.h>
#include <stdint.h>

#define TT 16384
#define DH 512
#define KK 128
#define SENT 0xAAAAAAAAu
#define CROWS 32
#define NCHUNK (TT / CROWS)   // 512
#define NPROJ 112
#define RSLOT 16

// Cross-block state in device globals (d_ws budget stays 2*TT*DH floats).
__device__ uint32_t g_ring[2][RSLOT][DH];   // parity-tagged h exchange rings
__device__ uint32_t g_flagXp[2][NCHUNK];    // Xp chunk-ready flags (1 = ready)

static __device__ __forceinline__ uint32_t aload(const uint32_t* p) {
    return __hip_atomic_load(p, __ATOMIC_RELAXED, __HIP_MEMORY_SCOPE_AGENT);
}
static __device__ __forceinline__ void astore(uint32_t* p, uint32_t v) {
    __hip_atomic_store(p, v, __ATOMIC_RELAXED, __HIP_MEMORY_SCOPE_AGENT);
}
static __device__ __forceinline__ float aloadf(const float* p) {
    return __uint_as_float(aload((const uint32_t*)p));
}

__global__ void init_kernel() {
    const int tid = threadIdx.x;
    uint32_t* r = &g_ring[0][0][0];
    for (int i = tid; i < 2 * RSLOT * DH; i += 1024) r[i] = SENT;   // bit31=1
    uint32_t* f = &g_flagXp[0][0];
    for (int i = tid; i < 2 * NCHUNK; i += 1024) f[i] = SENT;       // != 1
}

union __align__(16) SMem {
    struct { float inT[DH * 36]; float wt[32 * 516]; } proj;   // 139776 B
    struct { float ch[8][64]; float part[2][8][64]; uint32_t flag[8]; } scan;
};

// ---------------- projector: 32-row chunk GEMM  dst = src @ W (512 thr) ------
static __device__ void proj_chunk(SMem& sm, const float* __restrict__ W,
                                  const float* __restrict__ src, int srcMode,
                                  float* __restrict__ dst, uint32_t* flag, int t0)
{
    const int tid = threadIdx.x;
    #pragma unroll
    for (int i = 0; i < 32; ++i) {
        int idx = tid + 512 * i;           // 0..16383
        int row = idx >> 9;
        int col = idx & 511;
        float v;
        if (srcMode == 0) {
            v = src[(size_t)t0 * DH + idx];
        } else {
            const uint32_t* p = (const uint32_t*)src + (size_t)t0 * DH + idx;
            uint32_t u;
            while ((u = aload(p)) == SENT) __builtin_amdgcn_s_sleep(1);
            v = __uint_as_float(u);
        }
        sm.proj.inT[col * 36 + row] = v;
    }
    __syncthreads();

    const int rg = tid >> 6;     // rows 4rg..4rg+3
    const int cg = tid & 63;     // cols 8cg..8cg+7
    float acc[4][8];
    #pragma unroll
    for (int i = 0; i < 4; ++i)
        #pragma unroll
        for (int j = 0; j < 8; ++j) acc[i][j] = 0.f;

    for (int kt = 0; kt < 16; ++kt) {
        const int k0 = kt * 32;
        #pragma unroll
        for (int i = 0; i < 8; ++i) {               // stage 32x512 W tile
            int f4 = tid + 512 * i;                 // 0..4095 float4s
            int wr = f4 >> 7;
            int wc = (f4 & 127) << 2;
            *(float4*)&sm.proj.wt[wr * 516 + wc] =
                *(const float4*)&W[(size_t)(k0 + wr) * DH + wc];
        }
        __syncthreads();
        #pragma unroll 4
        for (int kk = 0; kk < 32; ++kk) {
            float4 a  = *(const float4*)&sm.proj.inT[(k0 + kk) * 36 + (rg << 2)];
            float4 w0 = *(const float4*)&sm.proj.wt[kk * 516 + (cg << 3)];
            float4 w1 = *(const float4*)&sm.proj.wt[kk * 516 + (cg << 3) + 4];
            float av[4] = {a.x, a.y, a.z, a.w};
            float wv[8] = {w0.x, w0.y, w0.z, w0.w, w1.x, w1.y, w1.z, w1.w};
            #pragma unroll
            for (int i = 0; i < 4; ++i)
                #pragma unroll
                for (int j = 0; j < 8; ++j) acc[i][j] += av[i] * wv[j];
        }
        __syncthreads();
    }
    #pragma unroll
    for (int i = 0; i < 4; ++i)
        #pragma unroll
        for (int j = 0; j < 8; ++j)
            astore((uint32_t*)&dst[(size_t)(t0 + (rg << 2) + i) * DH + (cg << 3) + j],
                   __float_as_uint(acc[i][j]));
    __threadfence();
    __syncthreads();
    if (tid == 0)
        __hip_atomic_store(flag, 1u, __ATOMIC_RELEASE, __HIP_MEMORY_SCOPE_AGENT);
}

// ---------------- fused persistent kernel (512 threads/block) ----------------
// Blocks 0..15: scan role, layer = b&1, slice = b>>1 (8 slices x 64 cols).
// Blocks 16..127: projectors for Xp0/Xp1.
__global__ __launch_bounds__(512, 1)
void fused(const float* __restrict__ X,
           const float* __restrict__ Wx0, const float* __restrict__ Wh0,
           const float* __restrict__ bh0, const float* __restrict__ h00,
           const float* __restrict__ Wx1, const float* __restrict__ Wh1,
           const float* __restrict__ bh1, const float* __restrict__ h01,
           float* H0r, float* H1r)
{
    __shared__ SMem sm;
    const int bIdx = blockIdx.x;
    const int tid = threadIdx.x;

    if (bIdx < 16) {
        // ================= scan role =================
        const int L     = bIdx & 1;
        const int slice = bIdx >> 1;          // 0..7
        const int w     = tid >> 6;           // wave 0..7 (wave 0 = reducer)
        const int lane  = tid & 63;
        const int colg  = (slice << 6) + lane;     // this lane's output column
        const int q     = (slice + w) & 7;         // input chunk this wave handles

        const float* Wh  = L ? Wh1 : Wh0;
        const float* bhv = L ? bh1 : bh0;
        const float* h0v = L ? h01 : h00;
        float* Hful      = L ? H1r : H0r;
        const float* Xp  = L ? H0r : H1r;     // Xp1 overlays H0, Xp0 overlays H1
        uint32_t* ring   = &g_ring[L][0][0];
        uint32_t* flagXp = &g_flagXp[L][0];

        // 64 weight VGPRs: wave w, lane -> col colg, inputs chunk q
        float wh[64];
        #pragma unroll
        for (int j = 0; j < 64; ++j)
            wh[j] = Wh[(size_t)((q << 6) + j) * DH + colg];
        const float bias = bhv[colg];

        if (tid < 8) sm.scan.flag[tid] = 0;
        __syncthreads();                      // one-time flag init

        float v_prev = 0.f, xp_cur = 0.f;
        int curCh = 0;
        if (w == 0) {
            v_prev = h0v[colg];
            while (__hip_atomic_load(&flagXp[0], __ATOMIC_ACQUIRE,
                                     __HIP_MEMORY_SCOPE_AGENT) != 1u) {}
            xp_cur = aloadf(&Xp[colg]);
        }

        for (int t = 0; t < TT; ++t) {
            // ---- obtain my chunk's 64 h-values ----
            float h;
            if (w == 0) {
                h = v_prev;                               // self chunk, in-register
            } else if (t == 0) {
                h = h0v[(q << 6) + lane];
            } else {
                const uint32_t par = (uint32_t)((t - 1) >> 4) & 1u;
                const uint32_t* p = &ring[(((t - 1) & 15) << 9) + (q << 6) + lane];
                uint32_t u;
                do { u = aload(p); } while ((u >> 31) != par);
                h = __uint_as_float(u & 0x7fffffffu);
            }
            // intra-wave LDS bounce (lockstep: all 64 values present at loop exit)
            sm.scan.ch[w][lane] = h;
            float acc = 0.f;
            const float4* h4 = (const float4*)sm.scan.ch[w];
            #pragma unroll
            for (int j = 0; j < 16; ++j) {
                float4 hv = h4[j];
                acc += wh[4*j+0]*hv.x + wh[4*j+1]*hv.y
                     + wh[4*j+2]*hv.z + wh[4*j+3]*hv.w;
            }

            if (w == 0) {
                // ---- reduce: spin per-wave flags, accumulate partials ----
                float sum = bias + xp_cur + acc;
                const int par = t & 1;
                for (int ww = 1; ww < 8; ++ww) {
                    while (__hip_atomic_load(&sm.scan.flag[ww], __ATOMIC_ACQUIRE,
                                             __HIP_MEMORY_SCOPE_WORKGROUP)
                           < (uint32_t)(t + 1)) {}
                    sum += sm.scan.part[par][ww][lane];
                }
                float v = fmaxf(sum, 0.f);
                const uint32_t hb = __float_as_uint(v);
                // ring store FIRST: remote pollers' critical path
                astore(&ring[((t & 15) << 9) + colg],
                       hb | ((uint32_t)((t >> 4) & 1u) << 31));
                astore((uint32_t*)&Hful[(size_t)t * DH + colg], hb);
                v_prev = v;
                if (t + 1 < TT) {             // xp prefetch in the shadow
                    const int ch = (t + 1) >> 5;
                    if (ch != curCh) {
                        while (__hip_atomic_load(&flagXp[ch], __ATOMIC_ACQUIRE,
                                                 __HIP_MEMORY_SCOPE_AGENT) != 1u) {}
                        curCh = ch;
                    }
                    xp_cur = aloadf(&Xp[(size_t)(t + 1) * DH + colg]);
                }
            } else {
                sm.scan.part[t & 1][w][lane] = acc;   // parity dbuf kills overwrite race
                if (lane == 0)
                    __hip_atomic_store(&sm.scan.flag[w], (uint32_t)(t + 1),
                                       __ATOMIC_RELEASE, __HIP_MEMORY_SCOPE_WORKGROUP);
            }
        }
    } else {
        // ================= projector role =================
        const int pi = bIdx - 16;             // 0..111
        for (int cc = pi; cc < NCHUNK; cc += NPROJ) {
            proj_chunk(sm, Wx0, X,   0, H1r /*Xp0*/, &g_flagXp[0][cc], cc * CROWS);
            proj_chunk(sm, Wx1, H0r, 1, H0r /*Xp1*/, &g_flagXp[1][cc], cc * CROWS);
        }
    }
}

// out[t][k] = dot(H1[t], W_log[k]) + b_log[k].  Block = 8 timesteps x 128 k.
__global__ __launch_bounds__(128, 1)
void logits_kernel(const float* __restrict__ H1, const float* __restrict__ Wl,
                   const float* __restrict__ bl, float* __restrict__ out)
{
    const int t0 = blockIdx.x * 8;
    const int k = threadIdx.x;

    __shared__ __align__(16) float hs[8 * DH];
    for (int idx = k; idx < 8 * DH / 4; idx += 128)
        ((float4*)hs)[idx] = ((const float4*)&H1[(size_t)t0 * DH])[idx];
    __syncthreads();

    float acc[8];
    const float bk = bl[k];
    #pragma unroll
    for (int r = 0; r < 8; ++r) acc[r] = bk;

    const float4* w4 = (const float4*)&Wl[(size_t)k * DH];
    for (int j = 0; j < DH / 4; ++j) {
        float4 w = w4[j];
        #pragma unroll
        for (int r = 0; r < 8; ++r) {
            float4 h = ((const float4*)&hs[r * DH])[j];
            acc[r] += w.x * h.x + w.y * h.y + w.z * h.z + w.w * h.w;
        }
    }
    #pragma unroll
    for (int r = 0; r < 8; ++r) out[(size_t)(t0 + r) * KK + k] = acc[r];
}

extern "C" void kernel_launch(void* const* d_in, const int* in_sizes, int n_in,
                              void* d_out, int out_size, void* d_ws, size_t ws_size,
                              hipStream_t stream)
{
    const float* X   = (const float*)d_in[0];
    const float* Wx0 = (const float*)d_in[1];
    const float* Wh0 = (const float*)d_in[2];
    const float* bh0 = (const float*)d_in[3];
    const float* h00 = (const float*)d_in[4];
    const float* Wx1 = (const float*)d_in[5];
    const float* Wh1 = (const float*)d_in[6];
    const float* bh1 = (const float*)d_in[7];
    const float* h01 = (const float*)d_in[8];
    const float* Wl  = (const float*)d_in[9];
    const float* bl  = (const float*)d_in[10];
    float* out = (float*)d_out;

    float* H0r = (float*)d_ws;                  // H0, later overlaid by Xp1
    float* H1r = H0r + (size_t)TT * DH;         // Xp0 first, then H1

    // H0 region must start at sentinel (harness poisons d_ws; defensive).
    hipMemsetAsync(d_ws, 0xAA, (size_t)TT * DH * sizeof(float), stream);
    hipLaunchKernelGGL(init_kernel, dim3(1), dim3(1024), 0, stream);
    hipLaunchKernelGGL(fused, dim3(16 + NPROJ), dim3(512), 0, stream,
                       X, Wx0, Wh0, bh0, h00, Wx1, Wh1, bh1, h01, H0r, H1r);
    hipLaunchKernelGGL(logits_kernel, dim3(TT / 8), dim3(128), 0, stream,
                       H1r, Wl, bl, out);
}